// Round 6
// baseline (366.280 us; speedup 1.0000x reference)
//
#include <hip/hip_runtime.h>
#include <math.h>

#define NN 131072      // nodes
#define NE 2097152     // edges
#define HD 32          // feature dim
#define NBUCK 256      // buckets of 512 nodes
#define BSH 9          // node >> 9 -> bucket
#define BNODES 512     // nodes per bucket
#define CHUNK 8192     // edges per binning block (NE/256)
#define MAXB 10240     // LDS stage capacity per bucket (max bucket ~8.5K)

__device__ __forceinline__ float softplus(float x) {
    return fmaxf(x, 0.f) + log1pf(expf(-fabsf(x)));
}
__device__ __forceinline__ float bf2f(unsigned short u) {
    return __uint_as_float(((unsigned int)u) << 16);
}
__device__ __forceinline__ float lo2f(unsigned int u) {   // low bf16 of packed pair
    return __uint_as_float(u << 16);
}
__device__ __forceinline__ float hi2f(unsigned int u) {   // high bf16 of packed pair
    return __uint_as_float(u & 0xFFFF0000u);
}
__device__ __forceinline__ unsigned short f2bf(float f) {   // round-to-nearest-even
    unsigned int u = __float_as_uint(f);
    return (unsigned short)((u + 0x7FFFu + ((u >> 16) & 1u)) >> 16);
}

// ---------- CSR build: block-private LDS counting sort (no global atomics) ----------

__global__ __launch_bounds__(256) void bin_kernel(
        const int* __restrict__ src, const int* __restrict__ dst,
        unsigned int* __restrict__ records,
        int* __restrict__ cnt_tab, int* __restrict__ off_tab) {
    __shared__ unsigned int stage[CHUNK];
    __shared__ int cntA[NBUCK], offA[NBUCK], wcur[NBUCK];
    int t = threadIdx.x, j = blockIdx.x;
    int base = j * CHUNK;
    cntA[t] = 0;
    __syncthreads();
    #pragma unroll 4
    for (int i = 0; i < CHUNK / 256; ++i) {
        int d = dst[base + t + i * 256];
        atomicAdd(&cntA[d >> BSH], 1);
    }
    __syncthreads();
    offA[t] = cntA[t];
    __syncthreads();
    for (int off = 1; off < NBUCK; off <<= 1) {
        int y = (t >= off) ? offA[t - off] : 0;
        __syncthreads();
        offA[t] += y;
        __syncthreads();
    }
    int excl = offA[t] - cntA[t];
    wcur[t] = excl;
    __syncthreads();
    #pragma unroll 4
    for (int i = 0; i < CHUNK / 256; ++i) {
        int e = base + t + i * 256;
        int d = dst[e], s = src[e];
        int slot = atomicAdd(&wcur[d >> BSH], 1);
        stage[slot] = ((unsigned int)(d & (BNODES - 1)) << 17) | (unsigned int)s;
    }
    __syncthreads();
    #pragma unroll 4
    for (int i = 0; i < CHUNK / 256; ++i)
        records[base + t + i * 256] = stage[t + i * 256];
    cnt_tab[j * NBUCK + t] = cntA[t];
    off_tab[j * NBUCK + t] = excl;
}

__global__ void bucket_scan_kernel(const int* __restrict__ cnt_tab,
                                   int* __restrict__ bucket_base,
                                   int* __restrict__ row_start) {
    __shared__ int tot[NBUCK];
    int t = threadIdx.x;
    int s = 0;
    for (int j = 0; j < 256; ++j) s += cnt_tab[j * NBUCK + t];
    tot[t] = s;
    __syncthreads();
    for (int off = 1; off < NBUCK; off <<= 1) {
        int y = (t >= off) ? tot[t - off] : 0;
        __syncthreads();
        tot[t] += y;
        __syncthreads();
    }
    bucket_base[t] = tot[t] - s;   // exclusive
    if (t == NBUCK - 1) {
        bucket_base[NBUCK] = tot[t];   // == NE
        row_start[NN] = tot[t];
    }
}

__global__ __launch_bounds__(512) void csr_sort_kernel(
        const unsigned int* __restrict__ records,
        const int* __restrict__ cnt_tab, const int* __restrict__ off_tab,
        const int* __restrict__ bucket_base,
        int* __restrict__ sorted_src, int* __restrict__ row_start,
        float* __restrict__ deg_inv) {
    __shared__ int stageS[MAXB];
    __shared__ int cnt[BNODES], rs[BNODES], wcur[BNODES];
    int t = threadIdx.x, b = blockIdx.x;
    int wave = t >> 6, lane = t & 63;   // 8 waves
    cnt[t] = 0;
    __syncthreads();
    for (int j = wave; j < 256; j += 8) {
        int c = cnt_tab[j * NBUCK + b];
        int sbase = j * CHUNK + off_tab[j * NBUCK + b];
        for (int k = lane; k < c; k += 64)
            atomicAdd(&cnt[records[sbase + k] >> 17], 1);
    }
    __syncthreads();
    rs[t] = cnt[t];
    __syncthreads();
    for (int off = 1; off < BNODES; off <<= 1) {
        int y = (t >= off) ? rs[t - off] : 0;
        __syncthreads();
        rs[t] += y;
        __syncthreads();
    }
    int excl = rs[t] - cnt[t];
    wcur[t] = excl;
    int gb = bucket_base[b];
    row_start[b * BNODES + t] = gb + excl;
    deg_inv[b * BNODES + t] = cnt[t] ? (1.0f / (float)cnt[t]) : 0.0f;
    __syncthreads();
    for (int j = wave; j < 256; j += 8) {
        int c = cnt_tab[j * NBUCK + b];
        int sbase = j * CHUNK + off_tab[j * NBUCK + b];
        for (int k = lane; k < c; k += 64) {
            unsigned int r = records[sbase + k];
            int slot = atomicAdd(&wcur[r >> 17], 1);
            stageS[slot] = (int)(r & 0x1FFFFu);
        }
    }
    __syncthreads();
    int btot = bucket_base[b + 1] - gb;
    for (int k = t; k < btot; k += 512) sorted_src[gb + k] = stageS[k];
}

// ---------- build interleaved layer-1 table: T1[n] = (feat[n] | feat[perm[n]]) bf16 ----------

__global__ __launch_bounds__(256) void build_T1_kernel(const float* __restrict__ feat,
                                                       const int* __restrict__ perm,
                                                       unsigned short* __restrict__ T1) {
    int i = blockIdx.x * 256 + threadIdx.x;   // over NN*64
    int n = i >> 6, l = i & 63;
    float v = (l < 32) ? feat[(n << 5) + l]
                       : feat[((size_t)perm[n] << 5) + (l - 32)];
    T1[i] = f2bf(v);
}

// ---------- fused dual GIN layer, wave-per-node, interleaved (pos|neg) rows ----------
// tab[n] = 64 bf16 (32 u32 words): elems 0-31 pos, 32-63 neg.
// Gather: u32-packed, 2 edges per wave load (lanes 0-31 even edge, 32-63 odd edge),
// unroll 8 -> 8 outstanding 256B wave loads.

__global__ __launch_bounds__(256) void layer_both_kernel(
        const unsigned short* __restrict__ tab,
        const float* __restrict__ W, const float* __restrict__ b,
        const int* __restrict__ row_start, const int* __restrict__ sorted_src,
        const float* __restrict__ deg_inv,
        unsigned short* __restrict__ outT) {
    __shared__ float Wl[1024];
    __shared__ float bl[32];
    int t = threadIdx.x;
    for (int i = t; i < 1024; i += 256) Wl[i] = W[i];
    if (t < 32) bl[t] = b[t];
    __syncthreads();

    const unsigned int* tab32 = (const unsigned int*)tab;
    int node = (blockIdx.x << 2) + (t >> 6);   // 4 waves -> 4 nodes
    int lane = t & 63;
    int w = lane & 31;        // u32 word within row
    int eh = lane >> 5;       // which edge of a pair this half handles
    int beg = row_start[node];
    int end = row_start[node + 1];
    int cnt = end - beg;

    unsigned int sw = tab32[((size_t)node << 5) + w];   // self word

    float ax0=0,ay0=0, ax1=0,ay1=0, ax2=0,ay2=0, ax3=0,ay3=0,
          ax4=0,ay4=0, ax5=0,ay5=0, ax6=0,ay6=0, ax7=0,ay7=0;
    int base = 0;
    while (base < cnt) {
        int rem = cnt - base;
        int chunk = rem > 64 ? 64 : rem;
        int idx = (lane < chunk) ? sorted_src[beg + base + lane] : 0;
        int npairs = chunk >> 1;
        int p = 0;
        for (; p + 8 <= npairs; p += 8) {
            int s0 = __shfl(idx, ((p+0)<<1) + eh, 64);
            int s1 = __shfl(idx, ((p+1)<<1) + eh, 64);
            int s2 = __shfl(idx, ((p+2)<<1) + eh, 64);
            int s3 = __shfl(idx, ((p+3)<<1) + eh, 64);
            int s4 = __shfl(idx, ((p+4)<<1) + eh, 64);
            int s5 = __shfl(idx, ((p+5)<<1) + eh, 64);
            int s6 = __shfl(idx, ((p+6)<<1) + eh, 64);
            int s7 = __shfl(idx, ((p+7)<<1) + eh, 64);
            unsigned int u0 = tab32[((size_t)s0 << 5) + w];
            unsigned int u1 = tab32[((size_t)s1 << 5) + w];
            unsigned int u2 = tab32[((size_t)s2 << 5) + w];
            unsigned int u3 = tab32[((size_t)s3 << 5) + w];
            unsigned int u4 = tab32[((size_t)s4 << 5) + w];
            unsigned int u5 = tab32[((size_t)s5 << 5) + w];
            unsigned int u6 = tab32[((size_t)s6 << 5) + w];
            unsigned int u7 = tab32[((size_t)s7 << 5) + w];
            ax0 += lo2f(u0); ay0 += hi2f(u0);
            ax1 += lo2f(u1); ay1 += hi2f(u1);
            ax2 += lo2f(u2); ay2 += hi2f(u2);
            ax3 += lo2f(u3); ay3 += hi2f(u3);
            ax4 += lo2f(u4); ay4 += hi2f(u4);
            ax5 += lo2f(u5); ay5 += hi2f(u5);
            ax6 += lo2f(u6); ay6 += hi2f(u6);
            ax7 += lo2f(u7); ay7 += hi2f(u7);
        }
        for (; p < npairs; ++p) {
            int s0 = __shfl(idx, (p<<1) + eh, 64);
            unsigned int u0 = tab32[((size_t)s0 << 5) + w];
            ax0 += lo2f(u0); ay0 += hi2f(u0);
        }
        if (chunk & 1) {
            int s0 = __shfl(idx, chunk - 1, 64);
            if (eh == 0) {   // lower half only: avoid double count after fold
                unsigned int u0 = tab32[((size_t)s0 << 5) + w];
                ax0 += lo2f(u0); ay0 += hi2f(u0);
            }
        }
        base += chunk;
    }
    float aggx = ((ax0+ax1)+(ax2+ax3))+((ax4+ax5)+(ax6+ax7));
    float aggy = ((ay0+ay1)+(ay2+ay3))+((ay4+ay5)+(ay6+ay7));
    aggx += __shfl_xor(aggx, 32, 64);   // fold even-edge + odd-edge sums
    aggy += __shfl_xor(aggy, 32, 64);

    float di = deg_inv[node];
    float vx = lo2f(sw) + aggx * di;    // row elem 2w
    float vy = hi2f(sw) + aggy * di;    // row elem 2w+1

    // GEMM: lanes 0-31 -> pos outputs, lanes 32-63 -> neg outputs (dim = lane&31).
    // v[k] of this half lives in word hb + (k>>1), element k&1.
    int hb = (lane < 32) ? 0 : 16;
    int j = lane & 31;
    float acc = bl[j];
    #pragma unroll
    for (int k = 0; k < 32; ++k) {
        float vk = __shfl((k & 1) ? vy : vx, hb + (k >> 1), 64);
        acc = fmaf(vk, Wl[(k << 5) + j], acc);
    }
    outT[((size_t)node << 6) + lane] = f2bf(fmaxf(acc, 0.f));
}

// ---------- readout ----------

__global__ __launch_bounds__(256) void colsum_kernel(const unsigned short* __restrict__ T,
                                                     float* __restrict__ colsum) {
    __shared__ float sd[256];
    int t = threadIdx.x;
    int stride = gridDim.x * 256;   // multiple of 32 -> column (idx&31) fixed per thread
    float acc = 0.f;
    for (int idx = blockIdx.x * 256 + t; idx < NN * 32; idx += stride)
        acc += bf2f(T[((idx >> 5) << 6) + (idx & 31)]);
    sd[t] = acc;
    __syncthreads();
    for (int off = 128; off >= 32; off >>= 1) {
        if (t < off) sd[t] += sd[t + off];
        __syncthreads();
    }
    if (t < 32) atomicAdd(&colsum[t], sd[t]);
}

__global__ void finalize_s_kernel(const float* __restrict__ colsum, const float* __restrict__ Wd,
                                  float* __restrict__ svec) {
    __shared__ float sm[32];
    int t = threadIdx.x;
    if (t < 32) {
        float m = colsum[t] / (float)NN;
        sm[t] = 1.f / (1.f + expf(-m));
    }
    __syncthreads();
    if (t < 32) {
        float acc = 0.f;
        for (int j = 0; j < 32; ++j) acc += Wd[t * 32 + j] * sm[j];
        svec[t] = acc;
    }
}

__global__ __launch_bounds__(256) void score_both_kernel(const unsigned short* __restrict__ T,
                                                         const float* __restrict__ svec,
                                                         float* __restrict__ loss) {
    __shared__ float sl[32];
    __shared__ float sdP[256];
    __shared__ float sdN[256];
    int t = threadIdx.x;
    if (t < 32) sl[t] = svec[t];
    __syncthreads();
    float accP = 0.f, accN = 0.f;
    int stride = gridDim.x * 256;
    for (int n = blockIdx.x * 256 + t; n < NN; n += stride) {
        const ushort4* row = (const ushort4*)(T + (n << 6));
        float dp = 0.f, dn = 0.f;
        #pragma unroll
        for (int q = 0; q < 8; ++q) {
            ushort4 a = row[q];       // pos half
            ushort4 c = row[q + 8];   // neg half
            dp += bf2f(a.x) * sl[4*q] + bf2f(a.y) * sl[4*q+1]
                + bf2f(a.z) * sl[4*q+2] + bf2f(a.w) * sl[4*q+3];
            dn += bf2f(c.x) * sl[4*q] + bf2f(c.y) * sl[4*q+1]
                + bf2f(c.z) * sl[4*q+2] + bf2f(c.w) * sl[4*q+3];
        }
        accP += softplus(-dp);   // target=1
        accN += softplus(dn);    // target=0
    }
    sdP[t] = accP; sdN[t] = accN;
    __syncthreads();
    for (int off = 128; off > 0; off >>= 1) {
        if (t < off) { sdP[t] += sdP[t + off]; sdN[t] += sdN[t + off]; }
        __syncthreads();
    }
    if (t == 0) { atomicAdd(&loss[0], sdP[0]); atomicAdd(&loss[1], sdN[0]); }
}

__global__ void final_kernel(const float* __restrict__ loss, float* __restrict__ out) {
    if (threadIdx.x == 0 && blockIdx.x == 0)
        out[0] = (loss[0] + loss[1]) / (float)NN;
}

// ---------- launch ----------

extern "C" void kernel_launch(void* const* d_in, const int* in_sizes, int n_in,
                              void* d_out, int out_size, void* d_ws, size_t ws_size,
                              hipStream_t stream) {
    const float* feature = (const float*)d_in[0];
    const float* W1 = (const float*)d_in[1];
    const float* b1 = (const float*)d_in[2];
    const float* W2 = (const float*)d_in[3];
    const float* b2 = (const float*)d_in[4];
    const float* Wd = (const float*)d_in[5];
    const int* src  = (const int*)d_in[6];
    const int* dst  = (const int*)d_in[7];
    const int* perm = (const int*)d_in[8];
    // d_in[9] = cluster_idx: irrelevant (equal-size disjoint clusters -> global mean)
    float* out = (float*)d_out;

    char* ws = (char*)d_ws;
    size_t off = 0;
    auto alloc = [&](size_t bytes) -> char* {
        char* p = ws + off;
        off += (bytes + 255) & ~(size_t)255;
        return p;
    };
    int*   row_start  = (int*)  alloc((size_t)(NN + 1) * 4);
    int*   sorted_src = (int*)  alloc((size_t)NE * 4);
    int*   cnt_tab    = (int*)  alloc((size_t)256 * NBUCK * 4);
    int*   off_tab    = (int*)  alloc((size_t)256 * NBUCK * 4);
    int*   bucket_base= (int*)  alloc((size_t)(NBUCK + 1) * 4);
    float* deg_inv    = (float*)alloc((size_t)NN * 4);
    unsigned short* T2 = (unsigned short*)alloc((size_t)NN * 64 * 2);  // 16 MB; records alias
    unsigned short* T1 = (unsigned short*)alloc((size_t)NN * 64 * 2);  // 16 MB; T3 alias
    float* colsum     = (float*)alloc(32 * 4);
    float* svec       = (float*)alloc(32 * 4);
    float* loss       = (float*)alloc(2 * 4);
    unsigned int* records = (unsigned int*)T2;   // dead before layer1 writes T2
    unsigned short* T3 = T1;                     // T1 dead after layer1

    hipMemsetAsync(colsum, 0, 32 * 4, stream);
    hipMemsetAsync(loss, 0, 2 * 4, stream);

    // CSR build: block-private counting sort, all writes coalesced
    bin_kernel<<<256, 256, 0, stream>>>(src, dst, records, cnt_tab, off_tab);
    bucket_scan_kernel<<<1, NBUCK, 0, stream>>>(cnt_tab, bucket_base, row_start);
    csr_sort_kernel<<<NBUCK, 512, 0, stream>>>(records, cnt_tab, off_tab, bucket_base,
                                               sorted_src, row_start, deg_inv);

    // interleaved feature table (pos | permuted)
    build_T1_kernel<<<(NN * 64) / 256, 256, 0, stream>>>(feature, perm, T1);

    // layer 1 + layer 2, each pos+neg in one wave-per-node pass
    layer_both_kernel<<<NN / 4, 256, 0, stream>>>(T1, W1, b1, row_start, sorted_src, deg_inv, T2);
    layer_both_kernel<<<NN / 4, 256, 0, stream>>>(T2, W2, b2, row_start, sorted_src, deg_inv, T3);

    // readout: s = Wd @ sigmoid(mean(pos))
    colsum_kernel<<<1024, 256, 0, stream>>>(T3, colsum);
    finalize_s_kernel<<<1, 64, 0, stream>>>(colsum, Wd, svec);

    // scores (pos + neg streaming over interleaved rows)
    score_both_kernel<<<1024, 256, 0, stream>>>(T3, svec, loss);

    final_kernel<<<1, 64, 0, stream>>>(loss, out);
}

// Round 7
// 354.639 us; speedup vs baseline: 1.0328x; 1.0328x over previous
//
#include <hip/hip_runtime.h>
#include <math.h>

#define NN 131072      // nodes
#define NE 2097152     // edges
#define HD 32          // feature dim
#define NBUCK 256      // buckets of 512 nodes
#define BSH 9          // node >> 9 -> bucket
#define BNODES 512     // nodes per bucket
#define CHUNK 8192     // edges per binning block (NE/256)
#define MAXB 10240     // LDS stage capacity per bucket (max bucket ~8.5K)

__device__ __forceinline__ float softplus(float x) {
    return fmaxf(x, 0.f) + log1pf(expf(-fabsf(x)));
}
__device__ __forceinline__ float bf2f(unsigned short u) {
    return __uint_as_float(((unsigned int)u) << 16);
}
__device__ __forceinline__ float lo2f(unsigned int u) {
    return __uint_as_float(u << 16);
}
__device__ __forceinline__ float hi2f(unsigned int u) {
    return __uint_as_float(u & 0xFFFF0000u);
}
__device__ __forceinline__ unsigned short f2bf(float f) {   // round-to-nearest-even
    unsigned int u = __float_as_uint(f);
    return (unsigned short)((u + 0x7FFFu + ((u >> 16) & 1u)) >> 16);
}
// ---- fp8 e4m3fn (OCP) helpers ----
__device__ __forceinline__ float fp8tof(unsigned int b8) {
    unsigned int em = b8 & 0x7Fu;
    float norm = __uint_as_float(0x3C000000u + (em << 20));  // (e+120)<<23 | m<<20
    float sub  = (float)(b8 & 7u) * 0.001953125f;            // m * 2^-9
    float mag  = (em >= 8u) ? norm : sub;
    return (b8 & 0x80u) ? -mag : mag;
}
__device__ __forceinline__ unsigned int f2fp8(float f) {     // RNE, clamp to ±448
    float a = fabsf(f);
    a = fminf(a, 448.f);
    unsigned int s = (__float_as_uint(f) >> 24) & 0x80u;
    unsigned int em;
    if (a >= 0.015625f) {     // normal
        unsigned int r = __float_as_uint(a);
        unsigned int t = r + 0x7FFFFu + ((r >> 20) & 1u);
        em = ((t >> 20) & 0x7FFu) - (120u << 3);
    } else {                  // subnormal: m * 2^-9
        em = (unsigned int)rintf(a * 512.f);
    }
    return s | em;
}

// ---------- CSR build: block-private LDS counting sort (no global atomics) ----------

__global__ __launch_bounds__(256) void bin_kernel(
        const int* __restrict__ src, const int* __restrict__ dst,
        unsigned int* __restrict__ records,
        int* __restrict__ cnt_tab, int* __restrict__ off_tab) {
    __shared__ unsigned int stage[CHUNK];
    __shared__ int cntA[NBUCK], offA[NBUCK], wcur[NBUCK];
    int t = threadIdx.x, j = blockIdx.x;
    int base = j * CHUNK;
    cntA[t] = 0;
    __syncthreads();
    #pragma unroll 4
    for (int i = 0; i < CHUNK / 256; ++i) {
        int d = dst[base + t + i * 256];
        atomicAdd(&cntA[d >> BSH], 1);
    }
    __syncthreads();
    offA[t] = cntA[t];
    __syncthreads();
    for (int off = 1; off < NBUCK; off <<= 1) {
        int y = (t >= off) ? offA[t - off] : 0;
        __syncthreads();
        offA[t] += y;
        __syncthreads();
    }
    int excl = offA[t] - cntA[t];
    wcur[t] = excl;
    __syncthreads();
    #pragma unroll 4
    for (int i = 0; i < CHUNK / 256; ++i) {
        int e = base + t + i * 256;
        int d = dst[e], s = src[e];
        int slot = atomicAdd(&wcur[d >> BSH], 1);
        stage[slot] = ((unsigned int)(d & (BNODES - 1)) << 17) | (unsigned int)s;
    }
    __syncthreads();
    #pragma unroll 4
    for (int i = 0; i < CHUNK / 256; ++i)
        records[base + t + i * 256] = stage[t + i * 256];
    cnt_tab[j * NBUCK + t] = cntA[t];
    off_tab[j * NBUCK + t] = excl;
}

__global__ void bucket_scan_kernel(const int* __restrict__ cnt_tab,
                                   int* __restrict__ bucket_base,
                                   int* __restrict__ row_start) {
    __shared__ int tot[NBUCK];
    int t = threadIdx.x;
    int s = 0;
    for (int j = 0; j < 256; ++j) s += cnt_tab[j * NBUCK + t];
    tot[t] = s;
    __syncthreads();
    for (int off = 1; off < NBUCK; off <<= 1) {
        int y = (t >= off) ? tot[t - off] : 0;
        __syncthreads();
        tot[t] += y;
        __syncthreads();
    }
    bucket_base[t] = tot[t] - s;   // exclusive
    if (t == NBUCK - 1) {
        bucket_base[NBUCK] = tot[t];   // == NE
        row_start[NN] = tot[t];
    }
}

__global__ __launch_bounds__(512) void csr_sort_kernel(
        const unsigned int* __restrict__ records,
        const int* __restrict__ cnt_tab, const int* __restrict__ off_tab,
        const int* __restrict__ bucket_base,
        int* __restrict__ sorted_src, int* __restrict__ row_start,
        float* __restrict__ deg_inv) {
    __shared__ int stageS[MAXB];
    __shared__ int cnt[BNODES], rs[BNODES], wcur[BNODES];
    int t = threadIdx.x, b = blockIdx.x;
    int wave = t >> 6, lane = t & 63;   // 8 waves
    cnt[t] = 0;
    __syncthreads();
    for (int j = wave; j < 256; j += 8) {
        int c = cnt_tab[j * NBUCK + b];
        int sbase = j * CHUNK + off_tab[j * NBUCK + b];
        for (int k = lane; k < c; k += 64)
            atomicAdd(&cnt[records[sbase + k] >> 17], 1);
    }
    __syncthreads();
    rs[t] = cnt[t];
    __syncthreads();
    for (int off = 1; off < BNODES; off <<= 1) {
        int y = (t >= off) ? rs[t - off] : 0;
        __syncthreads();
        rs[t] += y;
        __syncthreads();
    }
    int excl = rs[t] - cnt[t];
    wcur[t] = excl;
    int gb = bucket_base[b];
    row_start[b * BNODES + t] = gb + excl;
    deg_inv[b * BNODES + t] = cnt[t] ? (1.0f / (float)cnt[t]) : 0.0f;
    __syncthreads();
    for (int j = wave; j < 256; j += 8) {
        int c = cnt_tab[j * NBUCK + b];
        int sbase = j * CHUNK + off_tab[j * NBUCK + b];
        for (int k = lane; k < c; k += 64) {
            unsigned int r = records[sbase + k];
            int slot = atomicAdd(&wcur[r >> 17], 1);
            stageS[slot] = (int)(r & 0x1FFFFu);
        }
    }
    __syncthreads();
    int btot = bucket_base[b + 1] - gb;
    for (int k = t; k < btot; k += 512) sorted_src[gb + k] = stageS[k];
}

// ---------- build fp8 layer-1 gather table: G1[n] = fp8(feat[n] | feat[perm[n]]) ----------
// row = 64 fp8 = 16 u32 words; word w holds elems 4w..4w+3

__global__ __launch_bounds__(256) void build_G1_kernel(const float* __restrict__ feat,
                                                       const int* __restrict__ perm,
                                                       unsigned int* __restrict__ G1) {
    int i = blockIdx.x * 256 + threadIdx.x;   // over NN*16
    int n = i >> 4, w = i & 15;
    const float* sr = (w < 8) ? (feat + ((size_t)n << 5) + (w << 2))
                              : (feat + ((size_t)perm[n] << 5) + ((w - 8) << 2));
    float4 v = *(const float4*)sr;
    G1[i] = f2fp8(v.x) | (f2fp8(v.y) << 8) | (f2fp8(v.z) << 16) | (f2fp8(v.w) << 24);
}

// ---------- fused dual GIN layer, wave-per-node, fp8 gather (1 line/edge) ----------
// G row: 16 u32 = 64 fp8 (pos|neg). Quarter q of wave handles edge 4p+q; lane
// w=lane&15 owns elems 4w..4w+3. Self from f32 feat(+perm) if selfF, else bf16 T.

#define ACC4(u, X, Y, Z, Wv) { \
    X += fp8tof((u) & 0xFFu); Y += fp8tof(((u) >> 8) & 0xFFu); \
    Z += fp8tof(((u) >> 16) & 0xFFu); Wv += fp8tof((u) >> 24); }

__global__ __launch_bounds__(256) void layer_both_kernel(
        const unsigned int* __restrict__ G,
        const unsigned int* __restrict__ Tself,   // bf16 rows (layer2) or null
        const float* __restrict__ selfF,          // f32 features (layer1) or null
        const int* __restrict__ perm,             // layer1 only
        const float* __restrict__ W, const float* __restrict__ b,
        const int* __restrict__ row_start, const int* __restrict__ sorted_src,
        const float* __restrict__ deg_inv,
        unsigned short* __restrict__ outT, unsigned int* __restrict__ outG) {
    __shared__ float Wl[1024];
    __shared__ float bl[32];
    int t = threadIdx.x;
    for (int i = t; i < 1024; i += 256) Wl[i] = W[i];
    if (t < 32) bl[t] = b[t];
    __syncthreads();

    int node = (blockIdx.x << 2) + (t >> 6);   // 4 waves -> 4 nodes
    int lane = t & 63;
    int w = lane & 15;
    int q = lane >> 4;
    int beg = row_start[node];
    int end = row_start[node + 1];
    int cnt = end - beg;

    float g0x=0,g0y=0,g0z=0,g0w=0, g1x=0,g1y=0,g1z=0,g1w=0,
          g2x=0,g2y=0,g2z=0,g2w=0, g3x=0,g3y=0,g3z=0,g3w=0;
    int base = 0;
    while (base < cnt) {
        int rem = cnt - base;
        int chunk = rem > 64 ? 64 : rem;
        int idx = (lane < chunk) ? sorted_src[beg + base + lane] : 0;
        int ns = chunk >> 2;
        int p = 0;
        for (; p + 4 <= ns; p += 4) {
            int s0 = __shfl(idx, ((p+0)<<2) + q, 64);
            int s1 = __shfl(idx, ((p+1)<<2) + q, 64);
            int s2 = __shfl(idx, ((p+2)<<2) + q, 64);
            int s3 = __shfl(idx, ((p+3)<<2) + q, 64);
            unsigned int u0 = G[((size_t)s0 << 4) + w];
            unsigned int u1 = G[((size_t)s1 << 4) + w];
            unsigned int u2 = G[((size_t)s2 << 4) + w];
            unsigned int u3 = G[((size_t)s3 << 4) + w];
            ACC4(u0, g0x,g0y,g0z,g0w); ACC4(u1, g1x,g1y,g1z,g1w);
            ACC4(u2, g2x,g2y,g2z,g2w); ACC4(u3, g3x,g3y,g3z,g3w);
        }
        for (; p < ns; ++p) {
            int s0 = __shfl(idx, (p<<2) + q, 64);
            unsigned int u0 = G[((size_t)s0 << 4) + w];
            ACC4(u0, g0x,g0y,g0z,g0w);
        }
        int r = chunk & 3;
        if (r) {
            int slane = (ns << 2) + q;
            int s0 = __shfl(idx, slane < chunk ? slane : 0, 64);
            if (q < r) {
                unsigned int u0 = G[((size_t)s0 << 4) + w];
                ACC4(u0, g0x,g0y,g0z,g0w);
            }
        }
        base += chunk;
    }
    float ax = (g0x+g1x)+(g2x+g3x);
    float ay = (g0y+g1y)+(g2y+g3y);
    float az = (g0z+g1z)+(g2z+g3z);
    float aw = (g0w+g1w)+(g2w+g3w);
    ax += __shfl_xor(ax, 16, 64); ax += __shfl_xor(ax, 32, 64);
    ay += __shfl_xor(ay, 16, 64); ay += __shfl_xor(ay, 32, 64);
    az += __shfl_xor(az, 16, 64); az += __shfl_xor(az, 32, 64);
    aw += __shfl_xor(aw, 16, 64); aw += __shfl_xor(aw, 32, 64);

    float s0f, s1f, s2f, s3f;
    if (selfF) {
        int pn = perm[node];
        const float* sr = (w < 8) ? (selfF + ((size_t)node << 5) + (w << 2))
                                  : (selfF + ((size_t)pn << 5) + ((w - 8) << 2));
        float4 sv = *(const float4*)sr;
        s0f = sv.x; s1f = sv.y; s2f = sv.z; s3f = sv.w;
    } else {
        unsigned int t0 = Tself[((size_t)node << 5) + (w << 1)];
        unsigned int t1 = Tself[((size_t)node << 5) + (w << 1) + 1];
        s0f = lo2f(t0); s1f = hi2f(t0); s2f = lo2f(t1); s3f = hi2f(t1);
    }
    float di = deg_inv[node];
    float v0 = s0f + ax * di, v1 = s1f + ay * di;
    float v2 = s2f + az * di, v3 = s3f + aw * di;

    // GEMM: lanes 0-31 pos outputs, 32-63 neg (j = lane&31)
    int hb = (lane < 32) ? 0 : 8;
    int j = lane & 31;
    float acc = bl[j];
    #pragma unroll
    for (int k = 0; k < 32; ++k) {
        float vsrc = ((k & 3) == 0) ? v0 : ((k & 3) == 1) ? v1 : ((k & 3) == 2) ? v2 : v3;
        float vk = __shfl(vsrc, hb + (k >> 2), 64);
        acc = fmaf(vk, Wl[(k << 5) + j], acc);
    }
    acc = fmaxf(acc, 0.f);
    outT[((size_t)node << 6) + lane] = f2bf(acc);
    if (outG) {
        float c0 = __shfl(acc, (w << 2) + 0, 64);
        float c1 = __shfl(acc, (w << 2) + 1, 64);
        float c2 = __shfl(acc, (w << 2) + 2, 64);
        float c3 = __shfl(acc, (w << 2) + 3, 64);
        if (lane < 16)
            outG[((size_t)node << 4) + lane] =
                f2fp8(c0) | (f2fp8(c1) << 8) | (f2fp8(c2) << 16) | (f2fp8(c3) << 24);
    }
}

// ---------- readout ----------

__global__ __launch_bounds__(256) void colsum_kernel(const unsigned short* __restrict__ T,
                                                     float* __restrict__ colsum) {
    __shared__ float sd[256];
    int t = threadIdx.x;
    int stride = gridDim.x * 256;
    float acc = 0.f;
    for (int idx = blockIdx.x * 256 + t; idx < NN * 32; idx += stride)
        acc += bf2f(T[((idx >> 5) << 6) + (idx & 31)]);
    sd[t] = acc;
    __syncthreads();
    for (int off = 128; off >= 32; off >>= 1) {
        if (t < off) sd[t] += sd[t + off];
        __syncthreads();
    }
    if (t < 32) atomicAdd(&colsum[t], sd[t]);
}

__global__ void finalize_s_kernel(const float* __restrict__ colsum, const float* __restrict__ Wd,
                                  float* __restrict__ svec) {
    __shared__ float sm[32];
    int t = threadIdx.x;
    if (t < 32) {
        float m = colsum[t] / (float)NN;
        sm[t] = 1.f / (1.f + expf(-m));
    }
    __syncthreads();
    if (t < 32) {
        float acc = 0.f;
        for (int j = 0; j < 32; ++j) acc += Wd[t * 32 + j] * sm[j];
        svec[t] = acc;
    }
}

__global__ __launch_bounds__(256) void score_both_kernel(const unsigned short* __restrict__ T,
                                                         const float* __restrict__ svec,
                                                         float* __restrict__ loss) {
    __shared__ float sl[32];
    __shared__ float sdP[256];
    __shared__ float sdN[256];
    int t = threadIdx.x;
    if (t < 32) sl[t] = svec[t];
    __syncthreads();
    float accP = 0.f, accN = 0.f;
    int stride = gridDim.x * 256;
    for (int n = blockIdx.x * 256 + t; n < NN; n += stride) {
        const ushort4* row = (const ushort4*)(T + ((size_t)n << 6));
        float dp = 0.f, dn = 0.f;
        #pragma unroll
        for (int qq = 0; qq < 8; ++qq) {
            ushort4 a = row[qq];
            ushort4 c = row[qq + 8];
            dp += bf2f(a.x) * sl[4*qq] + bf2f(a.y) * sl[4*qq+1]
                + bf2f(a.z) * sl[4*qq+2] + bf2f(a.w) * sl[4*qq+3];
            dn += bf2f(c.x) * sl[4*qq] + bf2f(c.y) * sl[4*qq+1]
                + bf2f(c.z) * sl[4*qq+2] + bf2f(c.w) * sl[4*qq+3];
        }
        accP += softplus(-dp);   // target=1
        accN += softplus(dn);    // target=0
    }
    sdP[t] = accP; sdN[t] = accN;
    __syncthreads();
    for (int off = 128; off > 0; off >>= 1) {
        if (t < off) { sdP[t] += sdP[t + off]; sdN[t] += sdN[t + off]; }
        __syncthreads();
    }
    if (t == 0) { atomicAdd(&loss[0], sdP[0]); atomicAdd(&loss[1], sdN[0]); }
}

__global__ void final_kernel(const float* __restrict__ loss, float* __restrict__ out) {
    if (threadIdx.x == 0 && blockIdx.x == 0)
        out[0] = (loss[0] + loss[1]) / (float)NN;
}

// ---------- launch ----------

extern "C" void kernel_launch(void* const* d_in, const int* in_sizes, int n_in,
                              void* d_out, int out_size, void* d_ws, size_t ws_size,
                              hipStream_t stream) {
    const float* feature = (const float*)d_in[0];
    const float* W1 = (const float*)d_in[1];
    const float* b1 = (const float*)d_in[2];
    const float* W2 = (const float*)d_in[3];
    const float* b2 = (const float*)d_in[4];
    const float* Wd = (const float*)d_in[5];
    const int* src  = (const int*)d_in[6];
    const int* dst  = (const int*)d_in[7];
    const int* perm = (const int*)d_in[8];
    // d_in[9] = cluster_idx: irrelevant (equal-size disjoint clusters -> global mean)
    float* out = (float*)d_out;

    char* ws = (char*)d_ws;
    size_t off = 0;
    auto alloc = [&](size_t bytes) -> char* {
        char* p = ws + off;
        off += (bytes + 255) & ~(size_t)255;
        return p;
    };
    int*   row_start   = (int*)  alloc((size_t)(NN + 1) * 4);
    int*   sorted_src  = (int*)  alloc((size_t)NE * 4);
    int*   cnt_tab     = (int*)  alloc((size_t)256 * NBUCK * 4);
    int*   off_tab     = (int*)  alloc((size_t)256 * NBUCK * 4);
    int*   bucket_base = (int*)  alloc((size_t)(NBUCK + 1) * 4);
    float* deg_inv     = (float*)alloc((size_t)NN * 4);
    unsigned short* T2 = (unsigned short*)alloc((size_t)NN * 64 * 2);  // 16 MB
    unsigned int*   G1 = (unsigned int*)  alloc((size_t)NN * 16 * 4);  // 8 MB
    unsigned int*   G2 = (unsigned int*)  alloc((size_t)NN * 16 * 4);  // 8 MB
    float* colsum      = (float*)alloc(32 * 4);
    float* svec        = (float*)alloc(32 * 4);
    float* loss        = (float*)alloc(2 * 4);
    unsigned int* records = (unsigned int*)T2;   // dead before layer1 writes T2
    unsigned int* T2_32   = (unsigned int*)T2;

    hipMemsetAsync(colsum, 0, 32 * 4, stream);
    hipMemsetAsync(loss, 0, 2 * 4, stream);

    // CSR build (group edges by dst), all global writes coalesced
    bin_kernel<<<256, 256, 0, stream>>>(src, dst, records, cnt_tab, off_tab);
    bucket_scan_kernel<<<1, NBUCK, 0, stream>>>(cnt_tab, bucket_base, row_start);
    csr_sort_kernel<<<NBUCK, 512, 0, stream>>>(records, cnt_tab, off_tab, bucket_base,
                                               sorted_src, row_start, deg_inv);

    // fp8 gather table for layer 1
    build_G1_kernel<<<(NN * 16) / 256, 256, 0, stream>>>(feature, perm, G1);

    // layer 1: gathers G1(fp8), self from f32 feature(+perm); writes T2(bf16) + G2(fp8)
    layer_both_kernel<<<NN / 4, 256, 0, stream>>>(G1, nullptr, feature, perm, W1, b1,
                                                  row_start, sorted_src, deg_inv,
                                                  T2, G2);
    // layer 2: gathers G2(fp8), self from T2(bf16); writes T2 in-place (own row only)
    layer_both_kernel<<<NN / 4, 256, 0, stream>>>(G2, T2_32, nullptr, nullptr, W2, b2,
                                                  row_start, sorted_src, deg_inv,
                                                  T2, nullptr);

    // readout: s = Wd @ sigmoid(mean(pos))
    colsum_kernel<<<1024, 256, 0, stream>>>(T2, colsum);
    finalize_s_kernel<<<1, 64, 0, stream>>>(colsum, Wd, svec);

    // scores (pos + neg streaming over interleaved rows)
    score_both_kernel<<<1024, 256, 0, stream>>>(T2, svec, loss);

    final_kernel<<<1, 64, 0, stream>>>(loss, out);
}

// Round 8
// 341.794 us; speedup vs baseline: 1.0716x; 1.0376x over previous
//
#include <hip/hip_runtime.h>
#include <math.h>

#define NN 131072      // nodes
#define NE 2097152     // edges
#define HD 32          // feature dim
#define NBUCK 256      // buckets of 512 nodes
#define BSH 9          // node >> 9 -> bucket
#define BNODES 512     // nodes per bucket
#define CHUNK 8192     // edges per binning block (NE/256)
#define MAXB 10240     // LDS stage capacity per bucket (max bucket ~8.5K)

typedef float f32x2 __attribute__((ext_vector_type(2)));

__device__ __forceinline__ float softplus(float x) {
    return fmaxf(x, 0.f) + log1pf(expf(-fabsf(x)));
}
__device__ __forceinline__ float bf2f(unsigned short u) {
    return __uint_as_float(((unsigned int)u) << 16);
}
__device__ __forceinline__ float lo2f(unsigned int u) {
    return __uint_as_float(u << 16);
}
__device__ __forceinline__ float hi2f(unsigned int u) {
    return __uint_as_float(u & 0xFFFF0000u);
}
__device__ __forceinline__ unsigned short f2bf(float f) {   // round-to-nearest-even
    unsigned int u = __float_as_uint(f);
    return (unsigned short)((u + 0x7FFFu + ((u >> 16) & 1u)) >> 16);
}
// ---- fp8 e4m3fn (OCP) software fallback ----
__device__ __forceinline__ float fp8tof_sw(unsigned int b8) {
    unsigned int em = b8 & 0x7Fu;
    float norm = __uint_as_float(0x3C000000u + (em << 20));
    float sub  = (float)(b8 & 7u) * 0.001953125f;
    float mag  = (em >= 8u) ? norm : sub;
    return (b8 & 0x80u) ? -mag : mag;
}
__device__ __forceinline__ unsigned int f2fp8_sw(float f) {
    float a = fabsf(f);
    a = fminf(a, 448.f);
    unsigned int s = (__float_as_uint(f) >> 24) & 0x80u;
    unsigned int em;
    if (a >= 0.015625f) {
        unsigned int r = __float_as_uint(a);
        unsigned int t = r + 0x7FFFFu + ((r >> 20) & 1u);
        em = ((t >> 20) & 0x7FFu) - (120u << 3);
    } else {
        em = (unsigned int)rintf(a * 512.f);
    }
    return s | em;
}

// decode 4 fp8 from one u32 into 4 accumulators (HW pk-cvt if available)
#if __has_builtin(__builtin_amdgcn_cvt_pk_f32_fp8)
#define ACC4(u, X, Y, Z, Wv) { \
    f32x2 _lo = __builtin_amdgcn_cvt_pk_f32_fp8((int)(u), false); \
    f32x2 _hi = __builtin_amdgcn_cvt_pk_f32_fp8((int)(u), true);  \
    X += _lo[0]; Y += _lo[1]; Z += _hi[0]; Wv += _hi[1]; }
#else
#define ACC4(u, X, Y, Z, Wv) { \
    X += fp8tof_sw((u) & 0xFFu); Y += fp8tof_sw(((u) >> 8) & 0xFFu); \
    Z += fp8tof_sw(((u) >> 16) & 0xFFu); Wv += fp8tof_sw((u) >> 24); }
#endif

__device__ __forceinline__ unsigned int pack4_fp8(float a, float b, float c, float d) {
#if __has_builtin(__builtin_amdgcn_cvt_pk_fp8_f32)
    int v = 0;
    v = __builtin_amdgcn_cvt_pk_fp8_f32(a, b, v, false);
    v = __builtin_amdgcn_cvt_pk_fp8_f32(c, d, v, true);
    return (unsigned int)v;
#else
    return f2fp8_sw(a) | (f2fp8_sw(b) << 8) | (f2fp8_sw(c) << 16) | (f2fp8_sw(d) << 24);
#endif
}

// ---------- CSR build: block-private LDS counting sort (no global atomics) ----------

__global__ __launch_bounds__(256) void bin_kernel(
        const int* __restrict__ src, const int* __restrict__ dst,
        unsigned int* __restrict__ records,
        int* __restrict__ cnt_tab, int* __restrict__ off_tab) {
    __shared__ unsigned int stage[CHUNK];
    __shared__ int cntA[NBUCK], offA[NBUCK], wcur[NBUCK];
    int t = threadIdx.x, j = blockIdx.x;
    int base = j * CHUNK;
    cntA[t] = 0;
    __syncthreads();
    #pragma unroll 4
    for (int i = 0; i < CHUNK / 256; ++i) {
        int d = dst[base + t + i * 256];
        atomicAdd(&cntA[d >> BSH], 1);
    }
    __syncthreads();
    offA[t] = cntA[t];
    __syncthreads();
    for (int off = 1; off < NBUCK; off <<= 1) {
        int y = (t >= off) ? offA[t - off] : 0;
        __syncthreads();
        offA[t] += y;
        __syncthreads();
    }
    int excl = offA[t] - cntA[t];
    wcur[t] = excl;
    __syncthreads();
    #pragma unroll 4
    for (int i = 0; i < CHUNK / 256; ++i) {
        int e = base + t + i * 256;
        int d = dst[e], s = src[e];
        int slot = atomicAdd(&wcur[d >> BSH], 1);
        stage[slot] = ((unsigned int)(d & (BNODES - 1)) << 17) | (unsigned int)s;
    }
    __syncthreads();
    #pragma unroll 4
    for (int i = 0; i < CHUNK / 256; ++i)
        records[base + t + i * 256] = stage[t + i * 256];
    cnt_tab[j * NBUCK + t] = cntA[t];
    off_tab[j * NBUCK + t] = excl;
}

__global__ void bucket_scan_kernel(const int* __restrict__ cnt_tab,
                                   int* __restrict__ bucket_base,
                                   int* __restrict__ row_start) {
    __shared__ int tot[NBUCK];
    int t = threadIdx.x;
    int s = 0;
    for (int j = 0; j < 256; ++j) s += cnt_tab[j * NBUCK + t];
    tot[t] = s;
    __syncthreads();
    for (int off = 1; off < NBUCK; off <<= 1) {
        int y = (t >= off) ? tot[t - off] : 0;
        __syncthreads();
        tot[t] += y;
        __syncthreads();
    }
    bucket_base[t] = tot[t] - s;   // exclusive
    if (t == NBUCK - 1) {
        bucket_base[NBUCK] = tot[t];   // == NE
        row_start[NN] = tot[t];
    }
}

__global__ __launch_bounds__(512) void csr_sort_kernel(
        const unsigned int* __restrict__ records,
        const int* __restrict__ cnt_tab, const int* __restrict__ off_tab,
        const int* __restrict__ bucket_base,
        int* __restrict__ sorted_src, int* __restrict__ row_start,
        float* __restrict__ deg_inv) {
    __shared__ int stageS[MAXB];
    __shared__ int cnt[BNODES], rs[BNODES], wcur[BNODES];
    int t = threadIdx.x, b = blockIdx.x;
    int wave = t >> 6, lane = t & 63;   // 8 waves
    cnt[t] = 0;
    __syncthreads();
    for (int j = wave; j < 256; j += 8) {
        int c = cnt_tab[j * NBUCK + b];
        int sbase = j * CHUNK + off_tab[j * NBUCK + b];
        for (int k = lane; k < c; k += 64)
            atomicAdd(&cnt[records[sbase + k] >> 17], 1);
    }
    __syncthreads();
    rs[t] = cnt[t];
    __syncthreads();
    for (int off = 1; off < BNODES; off <<= 1) {
        int y = (t >= off) ? rs[t - off] : 0;
        __syncthreads();
        rs[t] += y;
        __syncthreads();
    }
    int excl = rs[t] - cnt[t];
    wcur[t] = excl;
    int gb = bucket_base[b];
    row_start[b * BNODES + t] = gb + excl;
    deg_inv[b * BNODES + t] = cnt[t] ? (1.0f / (float)cnt[t]) : 0.0f;
    __syncthreads();
    for (int j = wave; j < 256; j += 8) {
        int c = cnt_tab[j * NBUCK + b];
        int sbase = j * CHUNK + off_tab[j * NBUCK + b];
        for (int k = lane; k < c; k += 64) {
            unsigned int r = records[sbase + k];
            int slot = atomicAdd(&wcur[r >> 17], 1);
            stageS[slot] = (int)(r & 0x1FFFFu);
        }
    }
    __syncthreads();
    int btot = bucket_base[b + 1] - gb;
    for (int k = t; k < btot; k += 512) sorted_src[gb + k] = stageS[k];
}

// ---------- build fp8 layer-1 gather table: G1[n] = fp8(feat[n] | feat[perm[n]]) ----------

__global__ __launch_bounds__(256) void build_G1_kernel(const float* __restrict__ feat,
                                                       const int* __restrict__ perm,
                                                       unsigned int* __restrict__ G1) {
    int i = blockIdx.x * 256 + threadIdx.x;   // over NN*16
    int n = i >> 4, w = i & 15;
    const float* sr = (w < 8) ? (feat + ((size_t)n << 5) + (w << 2))
                              : (feat + ((size_t)perm[n] << 5) + ((w - 8) << 2));
    float4 v = *(const float4*)sr;
    G1[i] = pack4_fp8(v.x, v.y, v.z, v.w);
}

// ---------- fused dual GIN layer, wave-per-node, fp8 gather (1 line/edge) ----------
// G row: 16 u32 = 64 fp8 (pos|neg). Quarter q of wave handles edge 4p+q; lane
// w=lane&15 owns elems 4w..4w+3. Self from f32 feat(+perm) if selfF, else bf16 T.

__global__ __launch_bounds__(256) void layer_both_kernel(
        const unsigned int* __restrict__ G,
        const unsigned int* __restrict__ Tself,   // bf16 rows (layer2) or null
        const float* __restrict__ selfF,          // f32 features (layer1) or null
        const int* __restrict__ perm,             // layer1 only
        const float* __restrict__ W, const float* __restrict__ b,
        const int* __restrict__ row_start, const int* __restrict__ sorted_src,
        const float* __restrict__ deg_inv,
        unsigned short* __restrict__ outT, unsigned int* __restrict__ outG) {
    __shared__ float Wl[1024];
    __shared__ float bl[32];
    int t = threadIdx.x;
    for (int i = t; i < 1024; i += 256) Wl[i] = W[i];
    if (t < 32) bl[t] = b[t];
    __syncthreads();

    int node = (blockIdx.x << 2) + (t >> 6);   // 4 waves -> 4 nodes
    int lane = t & 63;
    int w = lane & 15;
    int q = lane >> 4;
    int beg = row_start[node];
    int end = row_start[node + 1];
    int cnt = end - beg;

    float g0x=0,g0y=0,g0z=0,g0w=0, g1x=0,g1y=0,g1z=0,g1w=0,
          g2x=0,g2y=0,g2z=0,g2w=0, g3x=0,g3y=0,g3z=0,g3w=0;
    int base = 0;
    while (base < cnt) {
        int rem = cnt - base;
        int chunk = rem > 64 ? 64 : rem;
        int idx = (lane < chunk) ? sorted_src[beg + base + lane] : 0;
        int ns = chunk >> 2;
        int p = 0;
        for (; p + 4 <= ns; p += 4) {
            int s0 = __shfl(idx, ((p+0)<<2) + q, 64);
            int s1 = __shfl(idx, ((p+1)<<2) + q, 64);
            int s2 = __shfl(idx, ((p+2)<<2) + q, 64);
            int s3 = __shfl(idx, ((p+3)<<2) + q, 64);
            unsigned int u0 = G[((size_t)s0 << 4) + w];
            unsigned int u1 = G[((size_t)s1 << 4) + w];
            unsigned int u2 = G[((size_t)s2 << 4) + w];
            unsigned int u3 = G[((size_t)s3 << 4) + w];
            ACC4(u0, g0x,g0y,g0z,g0w); ACC4(u1, g1x,g1y,g1z,g1w);
            ACC4(u2, g2x,g2y,g2z,g2w); ACC4(u3, g3x,g3y,g3z,g3w);
        }
        for (; p < ns; ++p) {
            int s0 = __shfl(idx, (p<<2) + q, 64);
            unsigned int u0 = G[((size_t)s0 << 4) + w];
            ACC4(u0, g0x,g0y,g0z,g0w);
        }
        int r = chunk & 3;
        if (r) {
            int slane = (ns << 2) + q;
            int s0 = __shfl(idx, slane < chunk ? slane : 0, 64);
            if (q < r) {
                unsigned int u0 = G[((size_t)s0 << 4) + w];
                ACC4(u0, g0x,g0y,g0z,g0w);
            }
        }
        base += chunk;
    }
    float ax = (g0x+g1x)+(g2x+g3x);
    float ay = (g0y+g1y)+(g2y+g3y);
    float az = (g0z+g1z)+(g2z+g3z);
    float aw = (g0w+g1w)+(g2w+g3w);
    ax += __shfl_xor(ax, 16, 64); ax += __shfl_xor(ax, 32, 64);
    ay += __shfl_xor(ay, 16, 64); ay += __shfl_xor(ay, 32, 64);
    az += __shfl_xor(az, 16, 64); az += __shfl_xor(az, 32, 64);
    aw += __shfl_xor(aw, 16, 64); aw += __shfl_xor(aw, 32, 64);

    float s0f, s1f, s2f, s3f;
    if (selfF) {
        int pn = perm[node];
        const float* sr = (w < 8) ? (selfF + ((size_t)node << 5) + (w << 2))
                                  : (selfF + ((size_t)pn << 5) + ((w - 8) << 2));
        float4 sv = *(const float4*)sr;
        s0f = sv.x; s1f = sv.y; s2f = sv.z; s3f = sv.w;
    } else {
        unsigned int t0 = Tself[((size_t)node << 5) + (w << 1)];
        unsigned int t1 = Tself[((size_t)node << 5) + (w << 1) + 1];
        s0f = lo2f(t0); s1f = hi2f(t0); s2f = lo2f(t1); s3f = hi2f(t1);
    }
    float di = deg_inv[node];
    float v0 = s0f + ax * di, v1 = s1f + ay * di;
    float v2 = s2f + az * di, v3 = s3f + aw * di;

    // GEMM: lanes 0-31 pos outputs, 32-63 neg (j = lane&31)
    int hb = (lane < 32) ? 0 : 8;
    int j = lane & 31;
    float acc = bl[j];
    #pragma unroll
    for (int k = 0; k < 32; ++k) {
        float vsrc = ((k & 3) == 0) ? v0 : ((k & 3) == 1) ? v1 : ((k & 3) == 2) ? v2 : v3;
        float vk = __shfl(vsrc, hb + (k >> 2), 64);
        acc = fmaf(vk, Wl[(k << 5) + j], acc);
    }
    acc = fmaxf(acc, 0.f);
    outT[((size_t)node << 6) + lane] = f2bf(acc);
    if (outG) {
        float c0 = __shfl(acc, (w << 2) + 0, 64);
        float c1 = __shfl(acc, (w << 2) + 1, 64);
        float c2 = __shfl(acc, (w << 2) + 2, 64);
        float c3 = __shfl(acc, (w << 2) + 3, 64);
        if (lane < 16)
            outG[((size_t)node << 4) + lane] = pack4_fp8(c0, c1, c2, c3);
    }
}

// ---------- readout ----------

__global__ __launch_bounds__(256) void colsum_kernel(const unsigned short* __restrict__ T,
                                                     float* __restrict__ colsum) {
    __shared__ float sd[256];
    int t = threadIdx.x;
    int stride = gridDim.x * 256;
    float acc = 0.f;
    for (int idx = blockIdx.x * 256 + t; idx < NN * 32; idx += stride)
        acc += bf2f(T[((idx >> 5) << 6) + (idx & 31)]);
    sd[t] = acc;
    __syncthreads();
    for (int off = 128; off >= 32; off >>= 1) {
        if (t < off) sd[t] += sd[t + off];
        __syncthreads();
    }
    if (t < 32) atomicAdd(&colsum[t], sd[t]);
}

__global__ void finalize_s_kernel(const float* __restrict__ colsum, const float* __restrict__ Wd,
                                  float* __restrict__ svec) {
    __shared__ float sm[32];
    int t = threadIdx.x;
    if (t < 32) {
        float m = colsum[t] / (float)NN;
        sm[t] = 1.f / (1.f + expf(-m));
    }
    __syncthreads();
    if (t < 32) {
        float acc = 0.f;
        for (int j = 0; j < 32; ++j) acc += Wd[t * 32 + j] * sm[j];
        svec[t] = acc;
    }
}

__global__ __launch_bounds__(256) void score_both_kernel(const unsigned short* __restrict__ T,
                                                         const float* __restrict__ svec,
                                                         float* __restrict__ loss) {
    __shared__ float sl[32];
    __shared__ float sdP[256];
    __shared__ float sdN[256];
    int t = threadIdx.x;
    if (t < 32) sl[t] = svec[t];
    __syncthreads();
    float accP = 0.f, accN = 0.f;
    int stride = gridDim.x * 256;
    for (int n = blockIdx.x * 256 + t; n < NN; n += stride) {
        const ushort4* row = (const ushort4*)(T + ((size_t)n << 6));
        float dp = 0.f, dn = 0.f;
        #pragma unroll
        for (int qq = 0; qq < 8; ++qq) {
            ushort4 a = row[qq];
            ushort4 c = row[qq + 8];
            dp += bf2f(a.x) * sl[4*qq] + bf2f(a.y) * sl[4*qq+1]
                + bf2f(a.z) * sl[4*qq+2] + bf2f(a.w) * sl[4*qq+3];
            dn += bf2f(c.x) * sl[4*qq] + bf2f(c.y) * sl[4*qq+1]
                + bf2f(c.z) * sl[4*qq+2] + bf2f(c.w) * sl[4*qq+3];
        }
        accP += softplus(-dp);   // target=1
        accN += softplus(dn);    // target=0
    }
    sdP[t] = accP; sdN[t] = accN;
    __syncthreads();
    for (int off = 128; off > 0; off >>= 1) {
        if (t < off) { sdP[t] += sdP[t + off]; sdN[t] += sdN[t + off]; }
        __syncthreads();
    }
    if (t == 0) { atomicAdd(&loss[0], sdP[0]); atomicAdd(&loss[1], sdN[0]); }
}

__global__ void final_kernel(const float* __restrict__ loss, float* __restrict__ out) {
    if (threadIdx.x == 0 && blockIdx.x == 0)
        out[0] = (loss[0] + loss[1]) / (float)NN;
}

// ---------- launch ----------

extern "C" void kernel_launch(void* const* d_in, const int* in_sizes, int n_in,
                              void* d_out, int out_size, void* d_ws, size_t ws_size,
                              hipStream_t stream) {
    const float* feature = (const float*)d_in[0];
    const float* W1 = (const float*)d_in[1];
    const float* b1 = (const float*)d_in[2];
    const float* W2 = (const float*)d_in[3];
    const float* b2 = (const float*)d_in[4];
    const float* Wd = (const float*)d_in[5];
    const int* src  = (const int*)d_in[6];
    const int* dst  = (const int*)d_in[7];
    const int* perm = (const int*)d_in[8];
    // d_in[9] = cluster_idx: irrelevant (equal-size disjoint clusters -> global mean)
    float* out = (float*)d_out;

    char* ws = (char*)d_ws;
    size_t off = 0;
    auto alloc = [&](size_t bytes) -> char* {
        char* p = ws + off;
        off += (bytes + 255) & ~(size_t)255;
        return p;
    };
    int*   row_start   = (int*)  alloc((size_t)(NN + 1) * 4);
    int*   sorted_src  = (int*)  alloc((size_t)NE * 4);
    int*   cnt_tab     = (int*)  alloc((size_t)256 * NBUCK * 4);
    int*   off_tab     = (int*)  alloc((size_t)256 * NBUCK * 4);
    int*   bucket_base = (int*)  alloc((size_t)(NBUCK + 1) * 4);
    float* deg_inv     = (float*)alloc((size_t)NN * 4);
    unsigned short* T2 = (unsigned short*)alloc((size_t)NN * 64 * 2);  // 16 MB
    unsigned int*   G1 = (unsigned int*)  alloc((size_t)NN * 16 * 4);  // 8 MB
    unsigned int*   G2 = (unsigned int*)  alloc((size_t)NN * 16 * 4);  // 8 MB
    float* colsum      = (float*)alloc(32 * 4);
    float* svec        = (float*)alloc(32 * 4);
    float* loss        = (float*)alloc(2 * 4);
    unsigned int* records = (unsigned int*)T2;   // dead before layer1 writes T2
    unsigned int* T2_32   = (unsigned int*)T2;

    hipMemsetAsync(colsum, 0, 32 * 4, stream);
    hipMemsetAsync(loss, 0, 2 * 4, stream);

    // CSR build (group edges by dst), all global writes coalesced
    bin_kernel<<<256, 256, 0, stream>>>(src, dst, records, cnt_tab, off_tab);
    bucket_scan_kernel<<<1, NBUCK, 0, stream>>>(cnt_tab, bucket_base, row_start);
    csr_sort_kernel<<<NBUCK, 512, 0, stream>>>(records, cnt_tab, off_tab, bucket_base,
                                               sorted_src, row_start, deg_inv);

    // fp8 gather table for layer 1
    build_G1_kernel<<<(NN * 16) / 256, 256, 0, stream>>>(feature, perm, G1);

    // layer 1: gathers G1(fp8), self from f32 feature(+perm); writes T2(bf16) + G2(fp8)
    layer_both_kernel<<<NN / 4, 256, 0, stream>>>(G1, nullptr, feature, perm, W1, b1,
                                                  row_start, sorted_src, deg_inv,
                                                  T2, G2);
    // layer 2: gathers G2(fp8), self from T2(bf16); writes T2 in-place (own row only)
    layer_both_kernel<<<NN / 4, 256, 0, stream>>>(G2, T2_32, nullptr, nullptr, W2, b2,
                                                  row_start, sorted_src, deg_inv,
                                                  T2, nullptr);

    // readout: s = Wd @ sigmoid(mean(pos))
    colsum_kernel<<<1024, 256, 0, stream>>>(T2, colsum);
    finalize_s_kernel<<<1, 64, 0, stream>>>(colsum, Wd, svec);

    // scores (pos + neg streaming over interleaved rows)
    score_both_kernel<<<1024, 256, 0, stream>>>(T2, svec, loss);

    final_kernel<<<1, 64, 0, stream>>>(loss, out);
}

// Round 9
// 295.560 us; speedup vs baseline: 1.2393x; 1.1564x over previous
//
#include <hip/hip_runtime.h>
#include <math.h>

#define NN 131072      // nodes
#define NE 2097152     // edges
#define HD 32          // feature dim
#define NBUCK 256      // buckets of 512 nodes
#define BSH 9          // node >> 9 -> bucket
#define BNODES 512     // nodes per bucket
#define CHUNK 8192     // edges per binning block (NE/256)
#define MAXB 10240     // LDS stage capacity per bucket (max bucket ~8.5K)

typedef float f32x2 __attribute__((ext_vector_type(2)));
typedef short bfrag __attribute__((ext_vector_type(8)));   // 8 bf16 = 4 VGPR
typedef float ffrag __attribute__((ext_vector_type(4)));   // 4 f32 acc

__device__ __forceinline__ float softplus(float x) {
    return fmaxf(x, 0.f) + log1pf(expf(-fabsf(x)));
}
__device__ __forceinline__ float bf2f(unsigned short u) {
    return __uint_as_float(((unsigned int)u) << 16);
}
__device__ __forceinline__ float lo2f(unsigned int u) {
    return __uint_as_float(u << 16);
}
__device__ __forceinline__ float hi2f(unsigned int u) {
    return __uint_as_float(u & 0xFFFF0000u);
}
__device__ __forceinline__ unsigned short f2bf(float f) {   // round-to-nearest-even
    unsigned int u = __float_as_uint(f);
    return (unsigned short)((u + 0x7FFFu + ((u >> 16) & 1u)) >> 16);
}
// ---- fp8 e4m3fn software fallback ----
__device__ __forceinline__ float fp8tof_sw(unsigned int b8) {
    unsigned int em = b8 & 0x7Fu;
    float norm = __uint_as_float(0x3C000000u + (em << 20));
    float sub  = (float)(b8 & 7u) * 0.001953125f;
    float mag  = (em >= 8u) ? norm : sub;
    return (b8 & 0x80u) ? -mag : mag;
}
__device__ __forceinline__ unsigned int f2fp8_sw(float f) {
    float a = fabsf(f);
    a = fminf(a, 448.f);
    unsigned int s = (__float_as_uint(f) >> 24) & 0x80u;
    unsigned int em;
    if (a >= 0.015625f) {
        unsigned int r = __float_as_uint(a);
        unsigned int t = r + 0x7FFFFu + ((r >> 20) & 1u);
        em = ((t >> 20) & 0x7FFu) - (120u << 3);
    } else {
        em = (unsigned int)rintf(a * 512.f);
    }
    return s | em;
}

#if __has_builtin(__builtin_amdgcn_cvt_pk_f32_fp8)
#define ACC4(u, X, Y, Z, Wv) { \
    f32x2 _lo = __builtin_amdgcn_cvt_pk_f32_fp8((int)(u), false); \
    f32x2 _hi = __builtin_amdgcn_cvt_pk_f32_fp8((int)(u), true);  \
    X += _lo[0]; Y += _lo[1]; Z += _hi[0]; Wv += _hi[1]; }
#else
#define ACC4(u, X, Y, Z, Wv) { \
    X += fp8tof_sw((u) & 0xFFu); Y += fp8tof_sw(((u) >> 8) & 0xFFu); \
    Z += fp8tof_sw(((u) >> 16) & 0xFFu); Wv += fp8tof_sw((u) >> 24); }
#endif

__device__ __forceinline__ unsigned int pack4_fp8(float a, float b, float c, float d) {
#if __has_builtin(__builtin_amdgcn_cvt_pk_fp8_f32)
    int v = 0;
    v = __builtin_amdgcn_cvt_pk_fp8_f32(a, b, v, false);
    v = __builtin_amdgcn_cvt_pk_fp8_f32(c, d, v, true);
    return (unsigned int)v;
#else
    return f2fp8_sw(a) | (f2fp8_sw(b) << 8) | (f2fp8_sw(c) << 16) | (f2fp8_sw(d) << 24);
#endif
}

// ---------- CSR build: block-private LDS counting sort (no global atomics) ----------

__global__ __launch_bounds__(256) void bin_kernel(
        const int* __restrict__ src, const int* __restrict__ dst,
        unsigned int* __restrict__ records,
        int* __restrict__ cnt_tab, int* __restrict__ off_tab) {
    __shared__ unsigned int stage[CHUNK];
    __shared__ int cntA[NBUCK], offA[NBUCK], wcur[NBUCK];
    int t = threadIdx.x, j = blockIdx.x;
    int base = j * CHUNK;
    cntA[t] = 0;
    __syncthreads();
    #pragma unroll 4
    for (int i = 0; i < CHUNK / 256; ++i) {
        int d = dst[base + t + i * 256];
        atomicAdd(&cntA[d >> BSH], 1);
    }
    __syncthreads();
    offA[t] = cntA[t];
    __syncthreads();
    for (int off = 1; off < NBUCK; off <<= 1) {
        int y = (t >= off) ? offA[t - off] : 0;
        __syncthreads();
        offA[t] += y;
        __syncthreads();
    }
    int excl = offA[t] - cntA[t];
    wcur[t] = excl;
    __syncthreads();
    #pragma unroll 4
    for (int i = 0; i < CHUNK / 256; ++i) {
        int e = base + t + i * 256;
        int d = dst[e], s = src[e];
        int slot = atomicAdd(&wcur[d >> BSH], 1);
        stage[slot] = ((unsigned int)(d & (BNODES - 1)) << 17) | (unsigned int)s;
    }
    __syncthreads();
    #pragma unroll 4
    for (int i = 0; i < CHUNK / 256; ++i)
        records[base + t + i * 256] = stage[t + i * 256];
    cnt_tab[j * NBUCK + t] = cntA[t];
    off_tab[j * NBUCK + t] = excl;
}

__global__ void bucket_scan_kernel(const int* __restrict__ cnt_tab,
                                   int* __restrict__ bucket_base,
                                   int* __restrict__ row_start) {
    __shared__ int tot[NBUCK];
    int t = threadIdx.x;
    int s = 0;
    for (int j = 0; j < 256; ++j) s += cnt_tab[j * NBUCK + t];
    tot[t] = s;
    __syncthreads();
    for (int off = 1; off < NBUCK; off <<= 1) {
        int y = (t >= off) ? tot[t - off] : 0;
        __syncthreads();
        tot[t] += y;
        __syncthreads();
    }
    bucket_base[t] = tot[t] - s;   // exclusive
    if (t == NBUCK - 1) {
        bucket_base[NBUCK] = tot[t];   // == NE
        row_start[NN] = tot[t];
    }
}

__global__ __launch_bounds__(512) void csr_sort_kernel(
        const unsigned int* __restrict__ records,
        const int* __restrict__ cnt_tab, const int* __restrict__ off_tab,
        const int* __restrict__ bucket_base,
        int* __restrict__ sorted_src, int* __restrict__ row_start,
        float* __restrict__ deg_inv) {
    __shared__ int stageS[MAXB];
    __shared__ int cnt[BNODES], rs[BNODES], wcur[BNODES];
    int t = threadIdx.x, b = blockIdx.x;
    int wave = t >> 6, lane = t & 63;   // 8 waves
    cnt[t] = 0;
    __syncthreads();
    for (int j = wave; j < 256; j += 8) {
        int c = cnt_tab[j * NBUCK + b];
        int sbase = j * CHUNK + off_tab[j * NBUCK + b];
        for (int k = lane; k < c; k += 64)
            atomicAdd(&cnt[records[sbase + k] >> 17], 1);
    }
    __syncthreads();
    rs[t] = cnt[t];
    __syncthreads();
    for (int off = 1; off < BNODES; off <<= 1) {
        int y = (t >= off) ? rs[t - off] : 0;
        __syncthreads();
        rs[t] += y;
        __syncthreads();
    }
    int excl = rs[t] - cnt[t];
    wcur[t] = excl;
    int gb = bucket_base[b];
    row_start[b * BNODES + t] = gb + excl;
    deg_inv[b * BNODES + t] = cnt[t] ? (1.0f / (float)cnt[t]) : 0.0f;
    __syncthreads();
    for (int j = wave; j < 256; j += 8) {
        int c = cnt_tab[j * NBUCK + b];
        int sbase = j * CHUNK + off_tab[j * NBUCK + b];
        for (int k = lane; k < c; k += 64) {
            unsigned int r = records[sbase + k];
            int slot = atomicAdd(&wcur[r >> 17], 1);
            stageS[slot] = (int)(r & 0x1FFFFu);
        }
    }
    __syncthreads();
    int btot = bucket_base[b + 1] - gb;
    for (int k = t; k < btot; k += 512) sorted_src[gb + k] = stageS[k];
}

// ---------- build fp8 layer-1 gather table: G1[n] = fp8(feat[n] | feat[perm[n]]) ----------

__global__ __launch_bounds__(256) void build_G1_kernel(const float* __restrict__ feat,
                                                       const int* __restrict__ perm,
                                                       unsigned int* __restrict__ G1) {
    int i = blockIdx.x * 256 + threadIdx.x;   // over NN*16
    int n = i >> 4, w = i & 15;
    const float* sr = (w < 8) ? (feat + ((size_t)n << 5) + (w << 2))
                              : (feat + ((size_t)perm[n] << 5) + ((w - 8) << 2));
    float4 v = *(const float4*)sr;
    G1[i] = pack4_fp8(v.x, v.y, v.z, v.w);
}

// ---------- aggregation kernel (DS-free gather): V[n] = self + mean_agg(G) ----------
// wave per node; lane (q=lane>>4, w=lane&15); per-lane direct idx loads (no shfl);
// only DS: 8 fold shfl_xor at the end.

__global__ __launch_bounds__(256) void agg_kernel(
        const unsigned int* __restrict__ G,       // fp8 rows [NN][16 u32]
        const unsigned int* __restrict__ TselfB,  // bf16 rows [NN][32 u32] or null
        const float* __restrict__ selfF,          // f32 features (layer1) or null
        const int* __restrict__ perm,             // layer1 only
        const int* __restrict__ row_start, const int* __restrict__ sorted_src,
        const float* __restrict__ deg_inv,
        unsigned int* __restrict__ outV) {        // bf16 rows [NN][32 u32]; may alias TselfB
    int t = threadIdx.x;
    int node = (blockIdx.x << 2) + (t >> 6);   // 4 waves -> 4 nodes
    int lane = t & 63;
    int w = lane & 15;
    int q = lane >> 4;
    int beg = row_start[node];
    int cnt = row_start[node + 1] - beg;
    const int* sp = sorted_src + beg;

    float x0=0,y0=0,z0=0,w0=0, x1=0,y1=0,z1=0,w1=0,
          x2=0,y2=0,z2=0,w2=0, x3=0,y3=0,z3=0,w3=0;
    int full = cnt >> 4;                       // 16-edge groups (4 per q-slot)
    for (int pp = 0; pp < full; ++pp) {
        int e = (pp << 4) + q;
        int i0 = sp[e], i1 = sp[e + 4], i2 = sp[e + 8], i3 = sp[e + 12];
        unsigned int u0 = G[((size_t)i0 << 4) + w];
        unsigned int u1 = G[((size_t)i1 << 4) + w];
        unsigned int u2 = G[((size_t)i2 << 4) + w];
        unsigned int u3 = G[((size_t)i3 << 4) + w];
        ACC4(u0, x0,y0,z0,w0); ACC4(u1, x1,y1,z1,w1);
        ACC4(u2, x2,y2,z2,w2); ACC4(u3, x3,y3,z3,w3);
    }
    for (int e = (full << 4) + q; e < cnt; e += 4) {
        int i0 = sp[e];
        unsigned int u0 = G[((size_t)i0 << 4) + w];
        ACC4(u0, x0,y0,z0,w0);
    }
    float ax = (x0+x1)+(x2+x3);
    float ay = (y0+y1)+(y2+y3);
    float az = (z0+z1)+(z2+z3);
    float aw = (w0+w1)+(w2+w3);
    ax += __shfl_xor(ax, 16, 64); ax += __shfl_xor(ax, 32, 64);
    ay += __shfl_xor(ay, 16, 64); ay += __shfl_xor(ay, 32, 64);
    az += __shfl_xor(az, 16, 64); az += __shfl_xor(az, 32, 64);
    aw += __shfl_xor(aw, 16, 64); aw += __shfl_xor(aw, 32, 64);

    float s0f, s1f, s2f, s3f;
    if (selfF) {
        int pn = perm[node];
        const float* sr = (w < 8) ? (selfF + ((size_t)node << 5) + (w << 2))
                                  : (selfF + ((size_t)pn << 5) + ((w - 8) << 2));
        float4 sv = *(const float4*)sr;
        s0f = sv.x; s1f = sv.y; s2f = sv.z; s3f = sv.w;
    } else {
        uint2 sv = *(const uint2*)(TselfB + ((size_t)node << 5) + (w << 1));
        s0f = lo2f(sv.x); s1f = hi2f(sv.x); s2f = lo2f(sv.y); s3f = hi2f(sv.y);
    }
    float di = deg_inv[node];
    float v0 = s0f + ax * di, v1 = s1f + ay * di;
    float v2 = s2f + az * di, v3 = s3f + aw * di;
    if (q == 0) {
        uint2 o;
        o.x = (unsigned int)f2bf(v0) | ((unsigned int)f2bf(v1) << 16);
        o.y = (unsigned int)f2bf(v2) | ((unsigned int)f2bf(v3) << 16);
        *(uint2*)(outV + ((size_t)node << 5) + (w << 1)) = o;
    }
}

// ---------- MFMA GEMM: O = relu(V @ W + bias), V/O = [2NN][32] bf16 row-major ----------
// (interleaved pos|neg rows make the [NN][64] buffer exactly this matrix). In-place OK.

__global__ __launch_bounds__(256) void gemm_kernel(
        const unsigned short* __restrict__ V, const float* __restrict__ W,
        const float* __restrict__ bias, unsigned short* __restrict__ O) {
    int l = threadIdx.x & 63;
    int col = l & 15, oct = l >> 4;
    bfrag B0, B1;
    #pragma unroll
    for (int i = 0; i < 8; ++i) {
        B0[i] = (short)f2bf(W[(oct * 8 + i) * 32 + col]);
        B1[i] = (short)f2bf(W[(oct * 8 + i) * 32 + 16 + col]);
    }
    float bias0 = bias[col], bias1 = bias[col + 16];
    int wid = blockIdx.x * 4 + (threadIdx.x >> 6);
    int nw = gridDim.x * 4;
    int nrb = (2 * NN) / 16;
    for (int rb = wid; rb < nrb; rb += nw) {
        size_t rbase = (size_t)rb << 4;
        bfrag A = *(const bfrag*)(V + (rbase + (size_t)(l & 15)) * 32 + oct * 8);
        ffrag C0 = {bias0, bias0, bias0, bias0};
        ffrag C1 = {bias1, bias1, bias1, bias1};
        C0 = __builtin_amdgcn_mfma_f32_16x16x32_bf16(A, B0, C0, 0, 0, 0);
        C1 = __builtin_amdgcn_mfma_f32_16x16x32_bf16(A, B1, C1, 0, 0, 0);
        #pragma unroll
        for (int m = 0; m < 4; ++m) {
            size_t row = rbase + oct * 4 + m;
            O[row * 32 + col]      = f2bf(fmaxf(C0[m], 0.f));
            O[row * 32 + col + 16] = f2bf(fmaxf(C1[m], 0.f));
        }
    }
}

// ---------- bf16 table -> fp8 table (streaming) ----------

__global__ __launch_bounds__(256) void conv_fp8_kernel(const unsigned int* __restrict__ Tb,
                                                       unsigned int* __restrict__ Gout) {
    int i = blockIdx.x * 256 + threadIdx.x;   // over NN*16
    uint2 tv = *(const uint2*)(Tb + ((size_t)i << 1));
    Gout[i] = pack4_fp8(lo2f(tv.x), hi2f(tv.x), lo2f(tv.y), hi2f(tv.y));
}

// ---------- readout ----------

__global__ __launch_bounds__(256) void colsum_kernel(const unsigned short* __restrict__ T,
                                                     float* __restrict__ colsum) {
    __shared__ float sd[256];
    int t = threadIdx.x;
    int stride = gridDim.x * 256;
    float acc = 0.f;
    for (int idx = blockIdx.x * 256 + t; idx < NN * 32; idx += stride)
        acc += bf2f(T[((idx >> 5) << 6) + (idx & 31)]);
    sd[t] = acc;
    __syncthreads();
    for (int off = 128; off >= 32; off >>= 1) {
        if (t < off) sd[t] += sd[t + off];
        __syncthreads();
    }
    if (t < 32) atomicAdd(&colsum[t], sd[t]);
}

__global__ void finalize_s_kernel(const float* __restrict__ colsum, const float* __restrict__ Wd,
                                  float* __restrict__ svec) {
    __shared__ float sm[32];
    int t = threadIdx.x;
    if (t < 32) {
        float m = colsum[t] / (float)NN;
        sm[t] = 1.f / (1.f + expf(-m));
    }
    __syncthreads();
    if (t < 32) {
        float acc = 0.f;
        for (int j = 0; j < 32; ++j) acc += Wd[t * 32 + j] * sm[j];
        svec[t] = acc;
    }
}

__global__ __launch_bounds__(256) void score_both_kernel(const unsigned short* __restrict__ T,
                                                         const float* __restrict__ svec,
                                                         float* __restrict__ loss) {
    __shared__ float sl[32];
    __shared__ float sdP[256];
    __shared__ float sdN[256];
    int t = threadIdx.x;
    if (t < 32) sl[t] = svec[t];
    __syncthreads();
    float accP = 0.f, accN = 0.f;
    int stride = gridDim.x * 256;
    for (int n = blockIdx.x * 256 + t; n < NN; n += stride) {
        const ushort4* row = (const ushort4*)(T + ((size_t)n << 6));
        float dp = 0.f, dn = 0.f;
        #pragma unroll
        for (int qq = 0; qq < 8; ++qq) {
            ushort4 a = row[qq];
            ushort4 c = row[qq + 8];
            dp += bf2f(a.x) * sl[4*qq] + bf2f(a.y) * sl[4*qq+1]
                + bf2f(a.z) * sl[4*qq+2] + bf2f(a.w) * sl[4*qq+3];
            dn += bf2f(c.x) * sl[4*qq] + bf2f(c.y) * sl[4*qq+1]
                + bf2f(c.z) * sl[4*qq+2] + bf2f(c.w) * sl[4*qq+3];
        }
        accP += softplus(-dp);   // target=1
        accN += softplus(dn);    // target=0
    }
    sdP[t] = accP; sdN[t] = accN;
    __syncthreads();
    for (int off = 128; off > 0; off >>= 1) {
        if (t < off) { sdP[t] += sdP[t + off]; sdN[t] += sdN[t + off]; }
        __syncthreads();
    }
    if (t == 0) { atomicAdd(&loss[0], sdP[0]); atomicAdd(&loss[1], sdN[0]); }
}

__global__ void final_kernel(const float* __restrict__ loss, float* __restrict__ out) {
    if (threadIdx.x == 0 && blockIdx.x == 0)
        out[0] = (loss[0] + loss[1]) / (float)NN;
}

// ---------- launch ----------

extern "C" void kernel_launch(void* const* d_in, const int* in_sizes, int n_in,
                              void* d_out, int out_size, void* d_ws, size_t ws_size,
                              hipStream_t stream) {
    const float* feature = (const float*)d_in[0];
    const float* W1 = (const float*)d_in[1];
    const float* b1 = (const float*)d_in[2];
    const float* W2 = (const float*)d_in[3];
    const float* b2 = (const float*)d_in[4];
    const float* Wd = (const float*)d_in[5];
    const int* src  = (const int*)d_in[6];
    const int* dst  = (const int*)d_in[7];
    const int* perm = (const int*)d_in[8];
    // d_in[9] = cluster_idx: irrelevant (equal-size disjoint clusters -> global mean)
    float* out = (float*)d_out;

    char* ws = (char*)d_ws;
    size_t off = 0;
    auto alloc = [&](size_t bytes) -> char* {
        char* p = ws + off;
        off += (bytes + 255) & ~(size_t)255;
        return p;
    };
    int*   row_start   = (int*)  alloc((size_t)(NN + 1) * 4);
    int*   sorted_src  = (int*)  alloc((size_t)NE * 4);
    int*   cnt_tab     = (int*)  alloc((size_t)256 * NBUCK * 4);
    int*   off_tab     = (int*)  alloc((size_t)256 * NBUCK * 4);
    int*   bucket_base = (int*)  alloc((size_t)(NBUCK + 1) * 4);
    float* deg_inv     = (float*)alloc((size_t)NN * 4);
    unsigned short* X  = (unsigned short*)alloc((size_t)NN * 64 * 2);  // 16 MB multi-role
    unsigned int*   G1 = (unsigned int*)  alloc((size_t)NN * 16 * 4);  // 8 MB
    unsigned int*   G2 = (unsigned int*)  alloc((size_t)NN * 16 * 4);  // 8 MB
    float* colsum      = (float*)alloc(32 * 4);
    float* svec        = (float*)alloc(32 * 4);
    float* loss        = (float*)alloc(2 * 4);
    unsigned int* records = (unsigned int*)X;   // dead after csr_sort
    unsigned int* X32     = (unsigned int*)X;

    hipMemsetAsync(colsum, 0, 32 * 4, stream);
    hipMemsetAsync(loss, 0, 2 * 4, stream);

    // CSR build (group edges by dst), all global writes coalesced
    bin_kernel<<<256, 256, 0, stream>>>(src, dst, records, cnt_tab, off_tab);
    bucket_scan_kernel<<<1, NBUCK, 0, stream>>>(cnt_tab, bucket_base, row_start);
    csr_sort_kernel<<<NBUCK, 512, 0, stream>>>(records, cnt_tab, off_tab, bucket_base,
                                               sorted_src, row_start, deg_inv);

    // fp8 gather table for layer 1
    build_G1_kernel<<<(NN * 16) / 256, 256, 0, stream>>>(feature, perm, G1);

    // layer 1: agg (gather G1, self from f32 feat+perm) -> V1 in X; GEMM in-place -> T2 in X
    agg_kernel<<<NN / 4, 256, 0, stream>>>(G1, nullptr, feature, perm,
                                           row_start, sorted_src, deg_inv, X32);
    gemm_kernel<<<256, 256, 0, stream>>>(X, W1, b1, X);
    conv_fp8_kernel<<<(NN * 16) / 256, 256, 0, stream>>>(X32, G2);

    // layer 2: agg (gather G2, self from T2 rows) -> V2 in X (in-place per-row); GEMM in-place
    agg_kernel<<<NN / 4, 256, 0, stream>>>(G2, X32, nullptr, nullptr,
                                           row_start, sorted_src, deg_inv, X32);
    gemm_kernel<<<256, 256, 0, stream>>>(X, W2, b2, X);

    // readout: s = Wd @ sigmoid(mean(pos))
    colsum_kernel<<<1024, 256, 0, stream>>>(X, colsum);
    finalize_s_kernel<<<1, 64, 0, stream>>>(colsum, Wd, svec);

    // scores (pos + neg streaming over interleaved rows)
    score_both_kernel<<<1024, 256, 0, stream>>>(X, svec, loss);

    final_kernel<<<1, 64, 0, stream>>>(loss, out);
}